// Round 9
// baseline (101.791 us; speedup 1.0000x reference)
//
#include <hip/hip_runtime.h>
#include <hip/hip_bf16.h>

// Problem constants (B, L, H, HS, OUT) = (4, 512, 768, 64, 16)
#define Bc   4
#define Lc   512
#define Hc   768
#define HSc  64
#define OUTc 16
#define Pc   131328   // L*(L+1)/2
#define KC   128      // k-chunk
#define NCH  6        // 768/128

typedef float floatx4 __attribute__((ext_vector_type(4)));
typedef short bf16x8  __attribute__((ext_vector_type(8)));
typedef float f32x4   __attribute__((ext_vector_type(4)));

// ws (floats): q@0 [131072], k@131072, A@262144, Eq@294912, Ek@327680

__device__ __forceinline__ unsigned short f2bf(float f) {
    unsigned int u = __float_as_uint(f);
    return (unsigned short)((u + 0x7FFFu + ((u >> 16) & 1u)) >> 16);   // RNE
}

#define XPITCH 776   // x row pitch in bf16 (768+8): banks 4*l15%32 -> 2-way (free)
#define WPITCH 136   // w row pitch in bf16 (128+8): same 2-way pattern, 16B aligned

// Fused projection: block (mb, nh) = 16 tokens x 64-col half (nh=0 q, nh=1 k).
// Grid 256 x 256 thr (4 waves; wave w owns n-tile w*16).
// Stages x-tile bf16 in LDS once; per 128-k chunk stages W^T bf16 in LDS via
// coalesced fp32 loads + packed b32 writes; ds_read_b128 fragments -> MFMA.
// Epilogue fused: q/k store + A/Eq (nh=0) or Ek (nh=1) projections.
__global__ __launch_bounds__(256) void proj_kernel(
    const float* __restrict__ x,
    const float* __restrict__ Wq, const float* __restrict__ bq,
    const float* __restrict__ Wk, const float* __restrict__ bk,
    const float* __restrict__ Wb, const float* __restrict__ bb,
    float* __restrict__ qws, float* __restrict__ kws,
    float* __restrict__ Aws, float* __restrict__ Eqws, float* __restrict__ Ekws)
{
    __shared__ __align__(16) char lds_raw[16 * XPITCH * 2 + 64 * WPITCH * 2]; // 24832+17408
    unsigned short* lx = (unsigned short*)lds_raw;                   // [16][XPITCH]
    unsigned short* lw = (unsigned short*)(lds_raw + 16 * XPITCH * 2); // [64][WPITCH]
    float* lc = (float*)(lds_raw + 16 * XPITCH * 2);                 // [16][64] (reuses lw)

    const int tid  = threadIdx.x;
    const int bx   = blockIdx.x;
    const int mb   = bx >> 1;
    const int nh   = bx & 1;          // 0: q cols, 1: k cols
    const int m0   = mb * 16;
    const int w    = tid >> 6;
    const int lane = tid & 63;
    const int l15  = lane & 15;
    const int quad = lane >> 4;

    // Stage x tile (16 x 768) -> bf16 LDS, coalesced float4.
    {
        const float4* xg = (const float4*)(x + (size_t)m0 * Hc);   // 3072 float4
        #pragma unroll
        for (int i = 0; i < 12; ++i) {
            const int flat = tid + i * 256;
            const int row  = flat / 192;
            const int c4   = flat - row * 192;
            const float4 v = xg[flat];
            ushort4 o = make_ushort4(f2bf(v.x), f2bf(v.y), f2bf(v.z), f2bf(v.w));
            *(ushort4*)&lx[row * XPITCH + c4 * 4] = o;
        }
    }

    const float* Ws = nh ? Wk : Wq;   // block-uniform
    f32x4 acc = {0.f, 0.f, 0.f, 0.f};

    for (int c = 0; c < NCH; ++c) {
        const int k0 = c * KC;
        if (c) __syncthreads();       // protect lw while previous minis read it
        // Stage W^T half-chunk: lw[n][kk] = Ws[k0+kk][n], n 0..63, kk 0..127.
        // Loads: lanes sweep consecutive n -> 256B coalesced; pack 2 k per b32 write.
        #pragma unroll 4
        for (int i = 0; i < 16; ++i) {
            const int slot = tid + i * 256;    // 0..4095
            const int n  = slot & 63;
            const int kp = slot >> 6;          // 0..63
            const float w0 = Ws[(k0 + 2 * kp) * HSc + n];
            const float w1 = Ws[(k0 + 2 * kp + 1) * HSc + n];
            const unsigned int pk = (unsigned)f2bf(w0) | ((unsigned)f2bf(w1) << 16);
            *(unsigned int*)&lw[n * WPITCH + 2 * kp] = pk;
        }
        __syncthreads();                       // also covers x-stage for c==0
        #pragma unroll
        for (int m = 0; m < 4; ++m) {
            const int ko = m * 32 + quad * 8;
            const bf16x8 a = *(const bf16x8*)&lx[l15 * XPITCH + k0 + ko];
            const bf16x8 b = *(const bf16x8*)&lw[(w * 16 + l15) * WPITCH + ko];
            acc = __builtin_amdgcn_mfma_f32_16x16x32_bf16(a, b, acc, 0, 0, 0);
        }
    }
    __syncthreads();

    // Epilogue 1: bias + store q/k; stage block's 16x64 half in lc for phase 2.
    // D layout: col = l15 (n), row token = quad*4 + r (m89/m91).
    const int gcol = w * 16 + l15;
    const float bias = nh ? bk[gcol] : bq[gcol];
    float* dst = nh ? kws : qws;
    #pragma unroll
    for (int r = 0; r < 4; ++r) {
        const int tl = quad * 4 + r;
        const float v = acc[r] + bias;
        dst[(size_t)(m0 + tl) * HSc + gcol] = v;
        lc[tl * 64 + gcol] = v;
    }
    __syncthreads();

    // Epilogue 2: per-token projections through Wb (16 KB, L1/L2-hot).
    // nh=0: A[t] = q.Wb[0:64], Eq[t] = q.Wb[128:192]
    // nh=1: Ek[t] = k.(Wb[64:128]+Wb[192:256]) + bb   (pair adds Eq+Ek)
    if (nh == 0) {
        #pragma unroll
        for (int i = 0; i < 2; ++i) {
            const int slot = tid + i * 256;
            const int t  = slot >> 5;
            const int cc = slot & 31;
            const float* row = &lc[t * 64];
            const int tok = m0 + t;
            if (cc < 16) {
                float a = 0.f;
                #pragma unroll 8
                for (int h = 0; h < 64; ++h) a += row[h] * Wb[h * OUTc + cc];
                Aws[(size_t)tok * OUTc + cc] = a;
            } else {
                const int o = cc - 16;
                float ev = 0.f;
                #pragma unroll 8
                for (int h = 0; h < 64; ++h) ev += row[h] * Wb[(128 + h) * OUTc + o];
                Eqws[(size_t)tok * OUTc + o] = ev;
            }
        }
    } else {
        const int t = tid >> 4;
        const int o = tid & 15;
        const float* row = &lc[t * 64];
        const int tok = m0 + t;
        float ev = bb[o];
        #pragma unroll 8
        for (int h = 0; h < 64; ++h)
            ev += row[h] * (Wb[(64 + h) * OUTc + o] + Wb[(192 + h) * OUTc + o]);
        Ekws[(size_t)tok * OUTc + o] = ev;
    }
}

// Pair kernel (R6 tiled + Eq/Ek split): Grid (8, 32, 4): x = e-tile (64 e's),
// y = s-tile (16 s's), z = batch. Tiles below diagonal exit early.
// q/A in LDS; k row + E chunks register-resident across 16 s-iterations.
__global__ __launch_bounds__(256) void pair_kernel(
    const float* __restrict__ qws, const float* __restrict__ kws,
    const float* __restrict__ Aws, const float* __restrict__ Eqws,
    const float* __restrict__ Ekws, float* __restrict__ out)
{
    const int j = blockIdx.x;
    const int i = blockIdx.y;
    const int b = blockIdx.z;
    if (j < (i >> 2)) return;

    __shared__ alignas(16) float q_tile[16][64];
    __shared__ alignas(16) float A_tile[16][16];

    const int tid = threadIdx.x;
    const int s0 = i * 16;
    const int e0 = j * 64;

    {
        const int r = tid >> 4, c4 = tid & 15;
        ((float4*)q_tile[r])[c4] =
            ((const float4*)(qws + ((size_t)b * Lc + s0 + r) * HSc))[c4];
        if (tid < 64) {
            const int ra = tid >> 2, ca = tid & 3;
            ((float4*)A_tile[ra])[ca] =
                ((const float4*)(Aws + ((size_t)b * Lc + s0 + ra) * OUTc))[ca];
        }
    }
    __syncthreads();

    const int g = tid >> 2;
    const int l = tid & 3;
    const int e = e0 + g;

    const float4* kk = (const float4*)(kws + ((size_t)b * Lc + e) * HSc);
    const float4 kv0 = kk[l];
    const float4 kv1 = kk[4 + l];
    const float4 kv2 = kk[8 + l];
    const float4 kv3 = kk[12 + l];
    const float4 e1 = ((const float4*)(Eqws + ((size_t)b * Lc + e) * OUTc))[l];
    const float4 e2 = ((const float4*)(Ekws + ((size_t)b * Lc + e) * OUTc))[l];
    const float4 ev = make_float4(e1.x + e2.x, e1.y + e2.y, e1.z + e2.z, e1.w + e2.w);

    float* ob = out + (size_t)b * Pc * OUTc;

    #pragma unroll 8
    for (int sl = 0; sl < 16; ++sl) {
        const int s = s0 + sl;
        const float4* qq = (const float4*)q_tile[sl];
        const float4 qv0 = qq[l];
        const float4 qv1 = qq[4 + l];
        const float4 qv2 = qq[8 + l];
        const float4 qv3 = qq[12 + l];

        float sc = qv0.x * kv0.x + qv0.y * kv0.y + qv0.z * kv0.z + qv0.w * kv0.w
                 + qv1.x * kv1.x + qv1.y * kv1.y + qv1.z * kv1.z + qv1.w * kv1.w
                 + qv2.x * kv2.x + qv2.y * kv2.y + qv2.z * kv2.z + qv2.w * kv2.w
                 + qv3.x * kv3.x + qv3.y * kv3.y + qv3.z * kv3.z + qv3.w * kv3.w;
        sc += __shfl_xor(sc, 1);
        sc += __shfl_xor(sc, 2);

        if (e >= s) {
            const float4 av = ((const float4*)A_tile[sl])[l];
            const int row = s * (2 * Lc + 1 - s) / 2 + (e - s);
            floatx4 r;
            r.x = av.x + ev.x + sc;
            r.y = av.y + ev.y + sc;
            r.z = av.z + ev.z + sc;
            r.w = av.w + ev.w + sc;
            __builtin_nontemporal_store(r, (floatx4*)(ob + (size_t)row * OUTc) + l);
        }
    }
}

extern "C" void kernel_launch(void* const* d_in, const int* in_sizes, int n_in,
                              void* d_out, int out_size, void* d_ws, size_t ws_size,
                              hipStream_t stream) {
    const float* x  = (const float*)d_in[0];
    const float* Wq = (const float*)d_in[1];
    const float* bq = (const float*)d_in[2];
    const float* Wk = (const float*)d_in[3];
    const float* bk = (const float*)d_in[4];
    const float* Wb = (const float*)d_in[5];
    const float* bb = (const float*)d_in[6];

    float* ws   = (float*)d_ws;
    float* qws  = ws;
    float* kws  = ws + 131072;
    float* Aws  = ws + 262144;
    float* Eqws = ws + 294912;
    float* Ekws = ws + 327680;

    proj_kernel<<<dim3(256), dim3(256), 0, stream>>>(
        x, Wq, bq, Wk, bk, Wb, bb, qws, kws, Aws, Eqws, Ekws);
    pair_kernel<<<dim3(8, 32, 4), dim3(256), 0, stream>>>(
        qws, kws, Aws, Eqws, Ekws, (float*)d_out);
}